// Round 1
// 304.236 us; speedup vs baseline: 1.0074x; 1.0074x over previous
//
#include <hip/hip_runtime.h>

typedef __bf16 bf16_t;
typedef __attribute__((ext_vector_type(8))) __bf16 bf16x8;
typedef __attribute__((ext_vector_type(4))) float floatx4;

#define MFMA16(a, b, c) __builtin_amdgcn_mfma_f32_16x16x32_bf16((a), (b), (c), 0, 0, 0)
// async global->LDS, 16B/lane: lane i's 16B lands at ldsbase + i*16 (wave-uniform base)
#define GLOAD_LDS(g, l)                                                                      \
    __builtin_amdgcn_global_load_lds((const __attribute__((address_space(1))) unsigned int*)(g), \
                                     (__attribute__((address_space(3))) unsigned int*)(l), 16, 0, 0)
// counted waits + raw barrier (T3/T4): __syncthreads would drain vmcnt(0) and empty the HBM queue
#define WAITV(N) asm volatile("s_waitcnt vmcnt(" #N ")" ::: "memory")
#define WAITL0() asm volatile("s_waitcnt lgkmcnt(0)" ::: "memory")
#define BAR() __builtin_amdgcn_s_barrier()
#define PIN() __builtin_amdgcn_sched_barrier(0)

constexpr int TT = 128;   // sequence length
constexpr int CD = 384;   // n_emb
constexpr int HS = 64;    // head size
constexpr int BB = 1024;  // batch
constexpr int NCH = 12;   // K chunks of 32
constexpr int GRID = 512; // persistent: each block handles b and b+512

// ---- phase-1 LDS byte layout (double-buffered) + cross-batch prefetch region ----
// x chunk: 128 rows x 32 fp32 cols, staggered: pair p (rows 2p,2p+1) at [p*272, p*272+256), 16B pad
//   -> row r at (r>>1)*272 + (r&1)*128; 64 pairs * 272 = 17408 B = 17 staging instrs exactly
// w chunk: 12 frags (3 proj x 4 nt) x 1024 B, chunk-major from wconv
// XPF: batch b+512's chunk-0 x, staged during batch b's phases 2-3 (disjoint from everything)
constexpr int XB0 = 0, XB1 = 17408, WB0 = 34816, WB1 = 47104, XPF = 59392;
constexpr int SMEM_BYTES = 76800;  // 75 KiB -> still 2 blocks/CU (2*76800 <= 163840)

// ---- phase-2 overlay (bf16 elements), unchanged (54272 B <= 59392, XPF untouched) ----
constexpr int QK_STR = 72;
constexpr int VT_STR = 136;
constexpr int QS_OFF = 0;
constexpr int KS_OFF = TT * QK_STR;
constexpr int VT_OFF = 2 * TT * QK_STR;
constexpr int PS_OFF = 0;

// ---- pre-kernel: weights -> bf16 fragments in CHUNK-MAJOR order ----
// frag f = (kki*3 + proj)*4 + nt ; wf[f*512 + lane*8 + j] = W_proj[16nt + (lane&15)][32kki + 8(lane>>4) + j]
__global__ void wconv_kernel(const float* __restrict__ wq, const float* __restrict__ wk,
                             const float* __restrict__ wv, bf16_t* __restrict__ wf) {
    const int t = blockIdx.x * 256 + threadIdx.x;
    if (t >= 144 * 64) return;
    const int lane = t & 63;
    const int f    = t >> 6;
    const int nt   = f & 3;
    const int proj = (f >> 2) % 3;
    const int kki  = f / 12;
    const float* W = (proj == 0) ? wq : ((proj == 1) ? wk : wv);
    const int h = 16 * nt + (lane & 15);
    const int c = 32 * kki + 8 * (lane >> 4);
    const float* src = W + h * CD + c;
    bf16x8 o;
#pragma unroll
    for (int j = 0; j < 8; ++j) o[j] = (bf16_t)src[j];
    *(bf16x8*)(wf + (size_t)t * 8) = o;
}

// ---- fused attention head: persistent 512 blocks x 2 batches, counted-vmcnt phase-1 pipeline ----
__launch_bounds__(256, 2)
__global__ void attn_kernel(const float* __restrict__ x, const bf16_t* __restrict__ wf,
                            float* __restrict__ out) {
    __shared__ __align__(16) char smem_raw[SMEM_BYTES];
    bf16_t* smem = (bf16_t*)smem_raw;
    const int lane = threadIdx.x & 63;
    const int w    = threadIdx.x >> 6;
    const int l15  = lane & 15;
    const int g    = lane >> 4;
    const char* wfb = (const char*)wf;

    // ---- per-lane x-staging map (computed once): instr i covers LDS bytes [i*1024,(i+1)*1024) ----
    // LDS byte u -> pair u/272; rem<256: row = 2p + (rem>>7), col byte = rem&127; else pad lane
    // per-chunk per-wave loads: wave0 = 5 x + 3 w = 8, waves1-3 = 4 x + 3 w = 7 (vmcnt math below)
    int      xi[5];
    unsigned xg[5];
#pragma unroll
    for (int t2 = 0; t2 < 5; ++t2) {
        const int i = w + 4 * t2;  // wave 0: 0,4,8,12,16 ; waves 1-3: 4 instrs
        xi[t2] = i;
        unsigned u   = (unsigned)i * 1024u + (unsigned)lane * 16u;
        unsigned p   = u / 272u;
        unsigned rem = u - 272u * p;
        unsigned row = 2u * p + (rem >> 7);
        xg[t2] = (rem < 256u) ? row * (CD * 4u) + (rem & 127u) : 0u;  // pad lanes read row 0 (harmless)
    }

    auto stage_x = [&](const char* xsrc, int boff) {
        char* xd = smem_raw + boff;
#pragma unroll
        for (int t2 = 0; t2 < 5; ++t2)
            if (xi[t2] <= 16) GLOAD_LDS(xsrc + xg[t2], xd + xi[t2] * 1024);
    };
    auto stage_w = [&](int c, int boff) {
        const char* wsrc = wfb + (size_t)(c * 12 + 3 * w) * 1024 + (size_t)lane * 16;
        char*       wd   = smem_raw + boff + 3 * w * 1024;
#pragma unroll
        for (int j = 0; j < 3; ++j) GLOAD_LDS(wsrc + (size_t)j * 1024, wd + j * 1024);
    };

    const char* xb0 = (const char*)(x + (size_t)blockIdx.x * TT * CD);
    const char* xb1 = (const char*)(x + (size_t)(blockIdx.x + GRID) * TT * CD);

    // it=0 prologue: 2-deep prefetch (chunks 0 and 1); PIN keeps the two groups FIFO-ordered
    stage_x(xb0, XB0);
    stage_w(0, WB0);
    PIN();
    stage_x(xb0 + 128, XB1);
    stage_w(1, WB1);

#pragma unroll 1
    for (int it = 0; it < 2; ++it) {
        const int   b    = blockIdx.x + it * GRID;
        const char* xcur = it ? xb1 : xb0;

        // ================= Phase 1: q,k,v projections =================
        floatx4 accq[2][4], acck[2][4], accv[2][4];
#pragma unroll
        for (int mt = 0; mt < 2; ++mt)
#pragma unroll
            for (int nt = 0; nt < 4; ++nt) {
                accq[mt][nt] = (floatx4)0.0f;
                acck[mt][nt] = (floatx4)0.0f;
                accv[mt][nt] = (floatx4)0.0f;
            }

        // chunk 0 resident; newest stage group (chunk 1 pair = 8/7 loads) stays in flight.
        // it=1: also drains XPF + epilogue stores + WB0 (all older than the newest pair).
        if (w == 0) WAITV(8); else WAITV(7);
        BAR();

#pragma unroll 1
        for (int c = 0; c < NCH; ++c) {
            const char* xs = (it == 1 && c == 0) ? smem_raw + XPF
                                                 : smem_raw + ((c & 1) ? XB1 : XB0);
            const char* ws = smem_raw + ((c & 1) ? WB1 : WB0);

            bf16x8 a[2];
#pragma unroll
            for (int mt = 0; mt < 2; ++mt) {
                const int   R = 32 * w + 16 * mt + l15;
                const char* p = xs + (R >> 1) * 272 + (R & 1) * 128 + 32 * g;
                float4 f0 = *(const float4*)p;
                float4 f1 = *(const float4*)(p + 16);
                bf16x8 t;
                t[0] = (bf16_t)f0.x; t[1] = (bf16_t)f0.y; t[2] = (bf16_t)f0.z; t[3] = (bf16_t)f0.w;
                t[4] = (bf16_t)f1.x; t[5] = (bf16_t)f1.y; t[6] = (bf16_t)f1.z; t[7] = (bf16_t)f1.w;
                a[mt] = t;
            }
            bf16x8 wbf[12];
#pragma unroll
            for (int pn = 0; pn < 12; ++pn)
                wbf[pn] = *(const bf16x8*)(ws + pn * 1024 + lane * 16);
#pragma unroll
            for (int nt = 0; nt < 4; ++nt) {
                accq[0][nt] = MFMA16(a[0], wbf[0 + nt], accq[0][nt]);
                accq[1][nt] = MFMA16(a[1], wbf[0 + nt], accq[1][nt]);
                acck[0][nt] = MFMA16(a[0], wbf[4 + nt], acck[0][nt]);
                acck[1][nt] = MFMA16(a[1], wbf[4 + nt], acck[1][nt]);
                accv[0][nt] = MFMA16(a[0], wbf[8 + nt], accv[0][nt]);
                accv[1][nt] = MFMA16(a[1], wbf[8 + nt], accv[1][nt]);
            }

            WAITL0();  // my ds_reads retired -> buffers reusable once everyone passes B1
            BAR();     // B1: all waves done READING chunk c's buffers
            if (c <= 9) {
                stage_x(xcur + (c + 2) * 128, (c & 1) ? XB1 : XB0);
                stage_w(c + 2, (c & 1) ? WB1 : WB0);
                // newest group (chunk c+2, 8/7 ops) stays in flight -> chunk c+1 landed
                if (w == 0) WAITV(8); else WAITV(7);
                BAR();  // B2: chunk c+1 resident for all waves
            } else if (c == 10) {
                if (it == 0) {
                    stage_x(xb1, XPF);  // cross-batch chunk-0 prefetch, flies through phases 2-3
                    if (w == 0) WAITV(5); else WAITV(4);  // chunk 11 landed, XPF in flight
                } else {
                    WAITV(0);  // tail: chunk 11 landed
                }
                BAR();
            }
            // c == 11: B1 only, fall out with all buffers consumed
        }

        // ---- write q,k as [t][h], v transposed as [h][t] into the (now dead) phase-1 area ----
#pragma unroll
        for (int mt = 0; mt < 2; ++mt)
#pragma unroll
            for (int nt = 0; nt < 4; ++nt) {
                const int t0 = 32 * w + 16 * mt + 4 * g;
                const int h  = 16 * nt + l15;
#pragma unroll
                for (int r = 0; r < 4; ++r) {
                    smem[QS_OFF + (t0 + r) * QK_STR + h] = (bf16_t)accq[mt][nt][r];
                    smem[KS_OFF + (t0 + r) * QK_STR + h] = (bf16_t)acck[mt][nt][r];
                    smem[VT_OFF + h * VT_STR + t0 + r]   = (bf16_t)accv[mt][nt][r];
                }
            }
        WAITL0();  // ds_writes visible
        BAR();     // qkv visible to all waves (no vmcnt drain: XPF stays in flight)

        // ================= Phase 2: S = q k^T (skip fully-masked causal tiles) =================
        floatx4 sacc[2][8];
#pragma unroll
        for (int mt = 0; mt < 2; ++mt)
#pragma unroll
            for (int nt = 0; nt < 8; ++nt) sacc[mt][nt] = (floatx4)0.0f;

#pragma unroll
        for (int kt = 0; kt < 2; ++kt) {
            const int hh = 32 * kt + 8 * g;
            bf16x8 aq[2];
            aq[0] = *(const bf16x8*)(smem + QS_OFF + (32 * w + l15) * QK_STR + hh);
            aq[1] = *(const bf16x8*)(smem + QS_OFF + (32 * w + 16 + l15) * QK_STR + hh);
#pragma unroll
            for (int nt = 0; nt < 8; ++nt) {
                if (16 * nt <= 32 * w + 31) {
                    bf16x8 bk = *(const bf16x8*)(smem + KS_OFF + (16 * nt + l15) * QK_STR + hh);
                    if (16 * nt <= 32 * w + 15) sacc[0][nt] = MFMA16(aq[0], bk, sacc[0][nt]);
                    sacc[1][nt] = MFMA16(aq[1], bk, sacc[1][nt]);
                }
            }
        }
        WAITL0();  // q/k reads retired before P overlays them
        BAR();

        // ================= causal mask + softmax, P -> LDS bf16 =================
        const float scale = 0.05103103630798287f;  // 384^-0.5
#pragma unroll
        for (int mt = 0; mt < 2; ++mt) {
#pragma unroll
            for (int r = 0; r < 4; ++r) {
                const int t = 32 * w + 16 * mt + 4 * g + r;
                float vals[8];
                float vmax = -__builtin_inff();
#pragma unroll
                for (int nt = 0; nt < 8; ++nt) {
                    const int s = 16 * nt + l15;
                    float v = (s <= t) ? sacc[mt][nt][r] * scale : -__builtin_inff();
                    vals[nt] = v;
                    vmax = fmaxf(vmax, v);
                }
                vmax = fmaxf(vmax, __shfl_xor(vmax, 1));
                vmax = fmaxf(vmax, __shfl_xor(vmax, 2));
                vmax = fmaxf(vmax, __shfl_xor(vmax, 4));
                vmax = fmaxf(vmax, __shfl_xor(vmax, 8));
                float sum = 0.0f;
#pragma unroll
                for (int nt = 0; nt < 8; ++nt) {
                    float e = __expf(vals[nt] - vmax);
                    vals[nt] = e;
                    sum += e;
                }
                sum += __shfl_xor(sum, 1);
                sum += __shfl_xor(sum, 2);
                sum += __shfl_xor(sum, 4);
                sum += __shfl_xor(sum, 8);
                const float inv = 1.0f / sum;
#pragma unroll
                for (int nt = 0; nt < 8; ++nt)
                    smem[PS_OFF + t * VT_STR + 16 * nt + l15] = (bf16_t)(vals[nt] * inv);
            }
        }
        // no sync: each wave reads back only its own P rows

        // ================= O = P v (skip all-zero s-chunks past the causal edge) =================
        floatx4 oacc[2][4];
#pragma unroll
        for (int mt = 0; mt < 2; ++mt)
#pragma unroll
            for (int nt = 0; nt < 4; ++nt) oacc[mt][nt] = (floatx4)0.0f;

        for (int st = 0; st <= w; ++st) {
            const int ss = 32 * st + 8 * g;
            bf16x8 ap0 = *(const bf16x8*)(smem + PS_OFF + (32 * w + l15) * VT_STR + ss);
            bf16x8 ap1 = *(const bf16x8*)(smem + PS_OFF + (32 * w + 16 + l15) * VT_STR + ss);
#pragma unroll
            for (int nt = 0; nt < 4; ++nt) {
                bf16x8 bv = *(const bf16x8*)(smem + VT_OFF + (16 * nt + l15) * VT_STR + ss);
                oacc[0][nt] = MFMA16(ap0, bv, oacc[0][nt]);
                oacc[1][nt] = MFMA16(ap1, bv, oacc[1][nt]);
            }
        }

        float* ob = out + (size_t)b * TT * HS;
#pragma unroll
        for (int mt = 0; mt < 2; ++mt)
#pragma unroll
            for (int nt = 0; nt < 4; ++nt) {
                const int t0 = 32 * w + 16 * mt + 4 * g;
                const int h  = 16 * nt + l15;
#pragma unroll
                for (int r = 0; r < 4; ++r)
                    ob[(size_t)(t0 + r) * HS + h] = oacc[mt][nt][r];
            }

        // ---- transition to batch b+512: refill the pipeline while stores/XPF fly ----
        if (it == 0) {
            WAITL0();  // my P/VT ds_reads retired
            BAR();     // BT: all waves done with P/VT -> phase-1 buffers reusable
            stage_w(0, WB0);            // w chunk 0 (x chunk 0 already in XPF)
            PIN();                      // keep W0 older than the chunk-1 pair for FIFO vmcnt math
            stage_x(xb1 + 128, XB1);    // chunk 1
            stage_w(1, WB1);
            // the it=1 loop-top WAITV(8/7) drains XPF + stores + W0, leaves chunk-1 pair in flight
        }
    }
}

extern "C" void kernel_launch(void* const* d_in, const int* in_sizes, int n_in,
                              void* d_out, int out_size, void* d_ws, size_t ws_size,
                              hipStream_t stream) {
    // setup_inputs order: x, Wk, Wq, Wv
    const float* x  = (const float*)d_in[0];
    const float* wk = (const float*)d_in[1];
    const float* wq = (const float*)d_in[2];
    const float* wv = (const float*)d_in[3];
    float* out = (float*)d_out;

    bf16_t* wf = (bf16_t*)d_ws;  // chunk-major weight fragments: 144 KB

    wconv_kernel<<<36, 256, 0, stream>>>(wq, wk, wv, wf);
    attn_kernel<<<GRID, 256, 0, stream>>>(x, wf, out);
}